// Round 11
// baseline (160.277 us; speedup 1.0000x reference)
//
#include <hip/hip_runtime.h>
#include <math.h>

typedef _Float16 f16x8 __attribute__((ext_vector_type(8)));
typedef _Float16 f16x4 __attribute__((ext_vector_type(4)));
typedef float    f32x16 __attribute__((ext_vector_type(16)));
typedef unsigned int u32;

#define DEVINL __device__ __forceinline__

DEVINL float fast_sigmoid(float x) {
    x = fminf(fmaxf(x, -30.f), 30.f);
    return 1.0f / (1.0f + __expf(-x));
}
DEVINL float fast_tanh(float x) {
    x = fminf(fmaxf(x, -15.f), 15.f);
    float e = __expf(-2.f * x);
    return (1.f - e) / (1.f + e);
}
DEVINL f16x8 f16x8_zero() {
    f16x8 v;
    #pragma unroll
    for (int j = 0; j < 8; ++j) v[j] = (_Float16)0.f;
    return v;
}

#define TKY(t) ((t) < 25 ? (t) / 5 : 2)
#define TKX(t) ((t) < 25 ? (t) % 5 : 2)

// ---------------------------------------------------------------------------
// kT_prep: weight repack + zero-init of hA (2MB) and cfrA (4MB). (r8 verified)
// ---------------------------------------------------------------------------
__global__ void kT_prep(const float* __restrict__ w1, const float* __restrict__ w2,
                        const float* __restrict__ wx, const float* __restrict__ wh,
                        const float* __restrict__ bx, const float* __restrict__ bh,
                        _Float16* __restrict__ wk1F, _Float16* __restrict__ w2F,
                        _Float16* __restrict__ wxF, _Float16* __restrict__ whF,
                        float* __restrict__ btot,
                        float* __restrict__ cfrA, _Float16* __restrict__ hA)
{
    int t = blockIdx.x * 256 + threadIdx.x;
    int stride = gridDim.x * 256;

    for (int i = t; i < 3 * 512; i += stride) {       // wk1F
        int j = i & 7, l = (i >> 3) & 63, q = i >> 9;
        int g = l >> 5, m = l & 31;
        int pr = 2 * q + g, pc = j;
        float v = 0.f;
        if (m < 16) {
            int oc = m >> 2, qy = (m >> 1) & 1, qx = m & 1;
            int ky = pr - qy, kx = pc - qx;
            if ((unsigned)ky < 5u && (unsigned)kx < 5u)
                v = w1[oc * 25 + ky * 5 + kx];
        }
        wk1F[i] = (_Float16)v;
    }
    for (int i = t; i < 12 * 512; i += stride) {      // w2F
        int j = i & 7, l = (i >> 3) & 63, q = i >> 9;
        int g = l >> 5, m = l & 31;
        int k = q * 16 + g * 8 + j;
        int pr = k >> 5, pc = (k >> 2) & 7, ic = k & 3;
        float v = 0.f;
        if (m < 16) {
            int oc = m >> 2, qy = (m >> 1) & 1, qx = m & 1;
            int ky = pr - qy, kx = pc - qx;
            if ((unsigned)ky < 5u && (unsigned)kx < 5u)
                v = w2[(oc * 4 + ic) * 25 + ky * 5 + kx];
        }
        w2F[i] = (_Float16)v;
    }
    for (int i = t; i < 10 * 512; i += stride) {      // wxF
        int j = i & 7, l = (i >> 3) & 63, q = i >> 9;
        int g = l >> 5, m = l & 31;
        int k = q * 16 + g * 8 + j;
        int pr = k >> 5, pc = (k >> 2) & 7, ic = k & 3;
        int og = (m & 3) * 8 + (m >> 2);
        float v = (pr < 5 && pc < 5) ? wx[(og * 4 + ic) * 25 + pr * 5 + pc] : 0.f;
        wxF[i] = (_Float16)v;
    }
    for (int i = t; i < 14 * 512; i += stride) {      // whF (j = ch' order)
        int j = i & 7, l = (i >> 3) & 63, q = i >> 9;
        int g = l >> 5, m = l & 31;
        int og = (m & 3) * 8 + (m >> 2);
        int tap = 2 * q + g;
        int icj = 2 * (j & 3) + (j >> 2);
        float v = (tap < 25) ? wh[(og * 8 + icj) * 25 + tap] : 0.f;
        whF[i] = (_Float16)v;
    }
    if (t < 32) {
        int og = (t & 3) * 8 + (t >> 2);
        btot[t] = bx[og] + bh[og];
    }
    float4 z4 = make_float4(0.f, 0.f, 0.f, 0.f);
    for (int i = t; i < 262144; i += stride) ((float4*)cfrA)[i] = z4;  // 4MB
    for (int i = t; i < 131072; i += stride) ((float4*)hA)[i]   = z4;  // 2MB
}

// ---------------------------------------------------------------------------
// k1: conv 1->4 + relu + maxpool2 as MFMA (pool-in-M). r8 verified verbatim.
// ---------------------------------------------------------------------------
__global__ __launch_bounds__(256, 4) void k1_mfma(
    const float* __restrict__ obs, const _Float16* __restrict__ wk1F,
    const float* __restrict__ b1, _Float16* __restrict__ s1cl)
{
    __shared__ _Float16 lds[36 * 264];
    u32* ldsu = (u32*)lds;
    int tid = threadIdx.x;
    int lane = tid & 63, w = tid >> 6, g = lane >> 5;
    int yt = blockIdx.x & 7;
    int tb = blockIdx.x >> 3;
    const float* in = obs + ((size_t)tb << 16);

    f16x8 wk1[3];
    #pragma unroll
    for (int q = 0; q < 3; ++q)
        wk1[q] = *(const f16x8*)(wk1F + ((size_t)q * 64 + lane) * 8);
    float bA = b1[g], bB = b1[g + 2];

    for (int i = tid; i < 36 * 132; i += 256) ldsu[i] = 0;
    __syncthreads();
    for (int i = tid; i < 36 * 64; i += 256) {
        int r = i >> 6, c4 = i & 63;
        int gy = (yt << 5) - 2 + r;
        if ((unsigned)gy < 256u) {
            float4 v = *(const float4*)(in + (gy << 8) + (c4 << 2));
            union { _Float16 h[2]; u32 u; } p0, p1;
            p0.h[0] = (_Float16)v.x; p0.h[1] = (_Float16)v.y;
            p1.h[0] = (_Float16)v.z; p1.h[1] = (_Float16)v.w;
            int ui = r * 132 + 1 + 2 * c4;
            ldsu[ui]     = p0.u;
            ldsu[ui + 1] = p1.u;
        }
    }
    __syncthreads();

    int y0 = yt << 4;
    #pragma unroll
    for (int i = 0; i < 16; ++i) {
        int py_loc = (w << 2) + (i >> 2);
        int px0 = (i & 3) << 5;
        int n = px0 + (lane & 31);
        const u32* lp = ldsu + (2 * py_loc + g) * 132 + n;

        f32x16 acc;
        #pragma unroll
        for (int r = 0; r < 16; ++r) acc[r] = 0.f;

        #pragma unroll
        for (int q = 0; q < 3; ++q) {
            union { f16x8 v; u32 u[4]; } bb;
            const u32* p = lp + (2 * q) * 132;
            bb.u[0] = p[0]; bb.u[1] = p[1]; bb.u[2] = p[2]; bb.u[3] = p[3];
            acc = __builtin_amdgcn_mfma_f32_32x32x16_f16(wk1[q], bb.v, acc, 0, 0, 0);
        }

        float mA = fmaxf(fmaxf(fmaxf(acc[0], acc[1]), fmaxf(acc[2], acc[3])) + bA, 0.f);
        float mB = fmaxf(fmaxf(fmaxf(acc[4], acc[5]), fmaxf(acc[6], acc[7])) + bB, 0.f);

        int pix = ((y0 + py_loc) << 7) + n;
        _Float16* dst = s1cl + (((size_t)tb << 14) + pix) * 4;
        dst[g]     = (_Float16)mA;
        dst[g + 2] = (_Float16)mB;
    }
}

// ---------------------------------------------------------------------------
// k2: conv 4->4 + relu + maxpool2 as MFMA (pool-in-M). r8 verified verbatim.
// ---------------------------------------------------------------------------
__global__ __launch_bounds__(256) void k2_mfma(
    const _Float16* __restrict__ s1cl, const _Float16* __restrict__ w2F,
    const float* __restrict__ b2, _Float16* __restrict__ s2cl)
{
    __shared__ _Float16 lds[20 * 136 * 4];
    int tid = threadIdx.x;
    int lane = tid & 63, w = tid >> 6, g = lane >> 5;
    int f  = blockIdx.x >> 3;
    int yt = blockIdx.x & 7;
    int y0 = yt << 3;

    f16x8 wf[12];
    #pragma unroll
    for (int q = 0; q < 12; ++q)
        wf[q] = *(const f16x8*)(w2F + ((size_t)q * 64 + lane) * 8);

    float bA = b2[g], bB = b2[g + 2];

    for (int i = tid; i < 20 * 68; i += 256) {
        int r = i / 68, u = i % 68;
        int gy = (yt << 4) - 2 + r;
        int gx = 2 * u - 2;
        f16x8 v = f16x8_zero();
        if ((unsigned)gy < 128u && (unsigned)gx < 127u)
            v = *(const f16x8*)(s1cl + ((((size_t)f << 14) + (gy << 7) + gx) << 2));
        *(f16x8*)&lds[(r * 136 + 2 * u) * 4] = v;
    }
    __syncthreads();

    #pragma unroll
    for (int i = 0; i < 4; ++i) {
        int ct = w * 4 + i;
        int ly = ct >> 1, hx = ct & 1;
        int px = hx * 32 + (lane & 31);
        int base = (2 * ly) * 1088 + (2 * px) * 8 + g * 16;

        f32x16 acc;
        #pragma unroll
        for (int r = 0; r < 16; ++r) acc[r] = 0.f;

        #pragma unroll
        for (int q = 0; q < 12; ++q) {
            f16x8 bv = *(const f16x8*)((const char*)lds + base +
                                       ((q >> 1) * 1088 + (q & 1) * 32));
            acc = __builtin_amdgcn_mfma_f32_32x32x16_f16(wf[q], bv, acc, 0, 0, 0);
        }

        float mA = fmaxf(fmaxf(fmaxf(acc[0], acc[1]), fmaxf(acc[2], acc[3])) + bA, 0.f);
        float mB = fmaxf(fmaxf(fmaxf(acc[4], acc[5]), fmaxf(acc[6], acc[7])) + bB, 0.f);

        int pix = ((y0 + ly) << 6) + px;
        _Float16* dst = s2cl + ((((size_t)f << 12) + pix) << 2);
        dst[g]     = (_Float16)mA;
        dst[g + 2] = (_Float16)mB;
    }
}

// ---------------------------------------------------------------------------
// k3: conv 4->32 gate precompute -> xg f16 fragment layout. r8 verified.
// ---------------------------------------------------------------------------
__global__ __launch_bounds__(256) void k3_mfma(
    const _Float16* __restrict__ s2cl, const _Float16* __restrict__ wxF,
    const float* __restrict__ btot, _Float16* __restrict__ xg)
{
    __shared__ _Float16 lds[12 * 72 * 4];
    int tid = threadIdx.x;
    int lane = tid & 63, w = tid >> 6, g = lane >> 5;
    int f  = blockIdx.x >> 3;
    int yt = blockIdx.x & 7;
    int y0 = yt << 3;

    f16x8 wf[10];
    #pragma unroll
    for (int q = 0; q < 10; ++q)
        wf[q] = *(const f16x8*)(wxF + ((size_t)q * 64 + lane) * 8);

    float bsel[16];
    #pragma unroll
    for (int r = 0; r < 16; ++r) {
        int row0 = (r & 3) + 8 * (r >> 2);
        bsel[r] = g ? btot[row0 + 4] : btot[row0];
    }

    for (int i = tid; i < 12 * 36; i += 256) {
        int r = i / 36, u = i % 36;
        int gy = y0 - 2 + r;
        int gx = 2 * u - 2;
        f16x8 v = f16x8_zero();
        if ((unsigned)gy < 64u && (unsigned)gx < 63u)
            v = *(const f16x8*)(s2cl + ((((size_t)f << 12) + (gy << 6) + gx) << 2));
        *(f16x8*)&lds[(r * 72 + 2 * u) * 4] = v;
    }
    __syncthreads();

    #pragma unroll
    for (int i = 0; i < 4; ++i) {
        int ct = w * 4 + i;
        int ly = ct >> 1, hx = ct & 1;
        int px = hx * 32 + (lane & 31);
        int base = ly * 576 + px * 8 + g * 16;

        f32x16 acc;
        #pragma unroll
        for (int q = 0; q < 16; ++q) acc[q] = 0.f;

        #pragma unroll
        for (int q = 0; q < 10; ++q) {
            f16x8 bv = *(const f16x8*)((const char*)lds + base +
                                       ((q >> 1) * 576 + (q & 1) * 32));
            acc = __builtin_amdgcn_mfma_f32_32x32x16_f16(wf[q], bv, acc, 0, 0, 0);
        }

        size_t tl = (size_t)f * 128 + (y0 + ly) * 2 + hx;
        f16x8 lo, hi;
        #pragma unroll
        for (int r = 0; r < 8; ++r) {
            lo[r] = (_Float16)(acc[r] + bsel[r]);
            hi[r] = (_Float16)(acc[r + 8] + bsel[r + 8]);
        }
        _Float16* dst = xg + tl * 1024 + lane * 16;
        *(f16x8*)dst       = lo;
        *(f16x8*)(dst + 8) = hi;
    }
}

// ---------------------------------------------------------------------------
// k4p: TWO ConvLSTM steps per launch (re-audited; r9 failure was k123's OOB).
// Block owns 4 h-rows; step t computed on rows y0-2..y0+5 (halo-redundant)
// into LDS; step t+1 consumes LDS. h/c ping-pong per LAUNCH (read old,
// write new -> no cross-block race). 512 blocks x 256 thr, 29,952 B LDS.
// ---------------------------------------------------------------------------
__global__ __launch_bounds__(256, 4) void k4p(
    const _Float16* __restrict__ xgA, const _Float16* __restrict__ xgB,
    const _Float16* __restrict__ hprev, _Float16* __restrict__ hnext,
    const float* __restrict__ cin, float* __restrict__ cout,
    const _Float16* __restrict__ whF,
    const float* __restrict__ wci, const float* __restrict__ wcf,
    const float* __restrict__ wco, float* __restrict__ out_hc, int last)
{
    __shared__ _Float16 sHp[12 * 68 * 8];   // h_{t-1} rows y0-4..y0+7
    __shared__ _Float16 sHt[8 * 68 * 8];    // h_t rows y0-2..y0+5
    __shared__ float    sC[8 * 4 * 64];     // c_t [ch8][row4][px64]
    int tid = threadIdx.x;
    int lane = tid & 63, w = tid >> 6, g = lane >> 5;
    int b  = blockIdx.x >> 4;
    int y0 = (blockIdx.x & 15) << 2;

    f16x8 wf[14];
    #pragma unroll
    for (int q = 0; q < 14; ++q)
        wf[q] = *(const f16x8*)(whF + ((size_t)q * 64 + lane) * 8);

    int toffs[14];
    #pragma unroll
    for (int q = 0; q < 14; ++q) {
        int t0 = 2 * q, t1 = 2 * q + 1;
        int o0 = TKY(t0) * 1088 + TKX(t0) * 16;
        int o1 = TKY(t1) * 1088 + TKX(t1) * 16;
        toffs[q] = g ? o1 : o0;
    }

    // zero sHt halo cols {0,1,66,67}
    u32* htU = (u32*)sHt;
    for (int i = tid; i < 128; i += 256) {
        int r = i >> 4, rem = i & 15;
        int col = rem >> 2; col = (col < 2) ? col : 64 + col;
        htU[(r * 68 + col) * 4 + (rem & 3)] = 0;
    }
    // stage h_{t-1} rows y0-4..y0+7
    for (int i = tid; i < 12 * 68; i += 256) {
        int r = i / 68, u = i % 68;
        int gy = y0 - 4 + r, gx = u - 2;
        f16x8 v = f16x8_zero();
        if ((unsigned)gy < 64u && (unsigned)gx < 64u)
            v = *(const f16x8*)(hprev + ((((size_t)b << 12) + (gy << 6) + gx) << 3));
        *(f16x8*)&sHp[(r * 68 + u) * 8] = v;
    }
    __syncthreads();

    // ---- step t: h_t rows y0-2..y0+5 -> sHt; c_t rows y0..y0+3 -> sC ----
    #pragma unroll
    for (int i = 0; i < 4; ++i) {
        int tt = (w << 2) + i;
        int ry = tt >> 1, hx = tt & 1;
        int gy = y0 - 2 + ry;
        int px = (hx << 5) + (lane & 31);
        f16x4 hv;
        #pragma unroll
        for (int j = 0; j < 4; ++j) hv[j] = (_Float16)0.f;

        if ((unsigned)gy < 64u) {                         // wave-uniform
            size_t tl = (size_t)b * 128 + gy * 2 + hx;
            const f16x8* xs = (const f16x8*)(xgA + tl * 1024 + (size_t)lane * 16);
            f16x8 xv0 = xs[0], xv1 = xs[1];
            float4 cv = *(const float4*)(cin + tl * 256 + lane * 4);

            f32x16 acc;
            #pragma unroll
            for (int r = 0; r < 8; ++r) {
                acc[r]     = (float)xv0[r];
                acc[r + 8] = (float)xv1[r];
            }
            int base = ry * 1088 + px * 16;
            #pragma unroll
            for (int q = 0; q < 14; ++q) {
                f16x8 bv = *(const f16x8*)((const char*)sHp + base + toffs[q]);
                acc = __builtin_amdgcn_mfma_f32_32x32x16_f16(wf[q], bv, acc, 0, 0, 0);
            }

            float cvv[4] = {cv.x, cv.y, cv.z, cv.w};
            int pp0 = (g << 12) + (gy << 6) + px;
            bool keepc = (ry >= 2 && ry < 6);             // rows y0..y0+3
            #pragma unroll
            for (int cc = 0; cc < 4; ++cc) {
                int ppix = pp0 + (cc << 13);              // ch = 2cc+g
                float c_old = cvv[cc];
                float i_ = fast_sigmoid(acc[4 * cc + 0] + c_old * wci[ppix]);
                float f_ = fast_sigmoid(acc[4 * cc + 1] + c_old * wcf[ppix]);
                float cn = f_ * c_old + i_ * fast_tanh(acc[4 * cc + 2]);
                float o_ = fast_sigmoid(acc[4 * cc + 3] + cn * wco[ppix]);
                hv[cc] = (_Float16)(o_ * fast_tanh(cn));
                if (keepc)
                    sC[((2 * cc + g) << 8) + ((ry - 2) << 6) + px] = cn;
            }
        }
        *(f16x4*)&sHt[(ry * 68 + px + 2) * 8 + (g << 2)] = hv;
    }
    __syncthreads();

    // ---- step t+1: rows y0..y0+3 from sHt/sC ----
    #pragma unroll
    for (int i = 0; i < 2; ++i) {
        int tt = (w << 1) + i;
        int r = tt >> 1, hx = tt & 1;
        int gy = y0 + r;
        int px = (hx << 5) + (lane & 31);
        size_t tl = (size_t)b * 128 + gy * 2 + hx;
        int pix = (gy << 6) + px;

        const f16x8* xs = (const f16x8*)(xgB + tl * 1024 + (size_t)lane * 16);
        f16x8 xv0 = xs[0], xv1 = xs[1];
        f32x16 acc;
        #pragma unroll
        for (int q = 0; q < 8; ++q) {
            acc[q]     = (float)xv0[q];
            acc[q + 8] = (float)xv1[q];
        }
        int base = r * 1088 + px * 16;
        #pragma unroll
        for (int q = 0; q < 14; ++q) {
            f16x8 bv = *(const f16x8*)((const char*)sHt + base + toffs[q]);
            acc = __builtin_amdgcn_mfma_f32_32x32x16_f16(wf[q], bv, acc, 0, 0, 0);
        }

        int pp0 = (g << 12) + pix;
        float cn4[4];
        f16x4 hv;
        #pragma unroll
        for (int cc = 0; cc < 4; ++cc) {
            int ppix = pp0 + (cc << 13);
            float c_old = sC[((2 * cc + g) << 8) + (r << 6) + px];
            float i_ = fast_sigmoid(acc[4 * cc + 0] + c_old * wci[ppix]);
            float f_ = fast_sigmoid(acc[4 * cc + 1] + c_old * wcf[ppix]);
            float cn = f_ * c_old + i_ * fast_tanh(acc[4 * cc + 2]);
            float o_ = fast_sigmoid(acc[4 * cc + 3] + cn * wco[ppix]);
            float hn = o_ * fast_tanh(cn);
            cn4[cc] = cn;
            hv[cc] = (_Float16)hn;
            if (last) {
                int ch = 2 * cc + g;
                size_t sidx = (((size_t)b * 8 + ch) << 12) + pix;
                out_hc[sidx] = hn;
                out_hc[sidx + 1048576] = cn;
            }
        }
        if (!last) {
            *(float4*)(cout + tl * 256 + lane * 4) =
                make_float4(cn4[0], cn4[1], cn4[2], cn4[3]);
            *(f16x4*)(hnext + ((((size_t)b << 12) + pix) << 3) + (g << 2)) = hv;
        }
    }
}

// ---------------------------------------------------------------------------
extern "C" void kernel_launch(void* const* d_in, const int* in_sizes, int n_in,
                              void* d_out, int out_size, void* d_ws, size_t ws_size,
                              hipStream_t stream)
{
    const float* obs = (const float*)d_in[0];
    const float* w1  = (const float*)d_in[1];
    const float* b1  = (const float*)d_in[2];
    const float* w2  = (const float*)d_in[3];
    const float* b2  = (const float*)d_in[4];
    const float* wx  = (const float*)d_in[5];
    const float* bx  = (const float*)d_in[6];
    const float* wh  = (const float*)d_in[7];
    const float* bh  = (const float*)d_in[8];
    const float* wci = (const float*)d_in[9];
    const float* wcf = (const float*)d_in[10];
    const float* wco = (const float*)d_in[11];

    char* wsb = (char*)d_ws;
    // byte layout:
    //   [0, 67,108,864)             xg f16 [32768 tl][1024]  (s1cl overlays)
    //   [0, 33,554,432)             s1cl f16 [256][16384][4] (dead after k2)
    //   [67,108,864, 75,497,472)    s2cl f16 [256][4096][4]
    //   [75,497,472, 77,594,624)    hA f16
    //   [77,594,624, 79,691,776)    hB f16
    //   [79,691,776, 83,886,080)    cfrA f32 [4096 tl][64][4]
    //   [83,886,080, 88,080,384)    cfrB f32
    //   [88,080,384, ...)           w2F, wxF, whF, wk1F, btot
    _Float16* xg   = (_Float16*)wsb;
    _Float16* s1cl = (_Float16*)wsb;
    _Float16* s2cl = (_Float16*)(wsb + 67108864);
    _Float16* hA   = (_Float16*)(wsb + 75497472);
    _Float16* hB   = (_Float16*)(wsb + 77594624);
    float*    cfrA = (float*)(wsb + 79691776);
    float*    cfrB = (float*)(wsb + 83886080);
    _Float16* w2F  = (_Float16*)(wsb + 88080384);
    _Float16* wxF  = (_Float16*)(wsb + 88092672);
    _Float16* whF  = (_Float16*)(wsb + 88102912);
    _Float16* wk1F = (_Float16*)(wsb + 88117248);
    float*    btot = (float*)(wsb + 88120320);

    kT_prep<<<64, 256, 0, stream>>>(w1, w2, wx, wh, bx, bh,
                                    wk1F, w2F, wxF, whF, btot, cfrA, hA);

    k1_mfma<<<2048, 256, 0, stream>>>(obs, wk1F, b1, s1cl);
    k2_mfma<<<2048, 256, 0, stream>>>(s1cl, w2F, b2, s2cl);
    k3_mfma<<<2048, 256, 0, stream>>>(s2cl, wxF, btot, xg);

    float* outp = (float*)d_out;
    const size_t XS = 4194304;   // f16 elements per time step
    k4p<<<512, 256, 0, stream>>>(xg,          xg + XS,     hA, hB, cfrA, cfrB,
                                 whF, wci, wcf, wco, outp, 0);
    k4p<<<512, 256, 0, stream>>>(xg + 2 * XS, xg + 3 * XS, hB, hA, cfrB, cfrA,
                                 whF, wci, wcf, wco, outp, 0);
    k4p<<<512, 256, 0, stream>>>(xg + 4 * XS, xg + 5 * XS, hA, hB, cfrA, cfrB,
                                 whF, wci, wcf, wco, outp, 0);
    k4p<<<512, 256, 0, stream>>>(xg + 6 * XS, xg + 7 * XS, hB, hA, cfrB, cfrA,
                                 whF, wci, wcf, wco, outp, 1);
}

// Round 12
// 138.117 us; speedup vs baseline: 1.1604x; 1.1604x over previous
//
#include <hip/hip_runtime.h>
#include <math.h>

typedef _Float16 f16x8 __attribute__((ext_vector_type(8)));
typedef _Float16 f16x4 __attribute__((ext_vector_type(4)));
typedef float    f32x16 __attribute__((ext_vector_type(16)));
typedef unsigned int u32;

#define DEVINL __device__ __forceinline__

DEVINL float fast_sigmoid(float x) {
    x = fminf(fmaxf(x, -30.f), 30.f);
    return 1.0f / (1.0f + __expf(-x));
}
DEVINL float fast_tanh(float x) {
    x = fminf(fmaxf(x, -15.f), 15.f);
    float e = __expf(-2.f * x);
    return (1.f - e) / (1.f + e);
}
DEVINL f16x8 f16x8_zero() {
    f16x8 v;
    #pragma unroll
    for (int j = 0; j < 8; ++j) v[j] = (_Float16)0.f;
    return v;
}

#define TKY(t) ((t) < 25 ? (t) / 5 : 2)
#define TKX(t) ((t) < 25 ? (t) % 5 : 2)

// ---------------------------------------------------------------------------
// kT_prep: weight repack + zero-init of hA (2MB) and cfr (4MB). (r8 verified)
// ---------------------------------------------------------------------------
__global__ void kT_prep(const float* __restrict__ w1, const float* __restrict__ w2,
                        const float* __restrict__ wx, const float* __restrict__ wh,
                        const float* __restrict__ bx, const float* __restrict__ bh,
                        _Float16* __restrict__ wk1F, _Float16* __restrict__ w2F,
                        _Float16* __restrict__ wxF, _Float16* __restrict__ whF,
                        float* __restrict__ btot,
                        float* __restrict__ cfr, _Float16* __restrict__ hA)
{
    int t = blockIdx.x * 256 + threadIdx.x;
    int stride = gridDim.x * 256;

    for (int i = t; i < 3 * 512; i += stride) {       // wk1F
        int j = i & 7, l = (i >> 3) & 63, q = i >> 9;
        int g = l >> 5, m = l & 31;
        int pr = 2 * q + g, pc = j;
        float v = 0.f;
        if (m < 16) {
            int oc = m >> 2, qy = (m >> 1) & 1, qx = m & 1;
            int ky = pr - qy, kx = pc - qx;
            if ((unsigned)ky < 5u && (unsigned)kx < 5u)
                v = w1[oc * 25 + ky * 5 + kx];
        }
        wk1F[i] = (_Float16)v;
    }
    for (int i = t; i < 12 * 512; i += stride) {      // w2F
        int j = i & 7, l = (i >> 3) & 63, q = i >> 9;
        int g = l >> 5, m = l & 31;
        int k = q * 16 + g * 8 + j;
        int pr = k >> 5, pc = (k >> 2) & 7, ic = k & 3;
        float v = 0.f;
        if (m < 16) {
            int oc = m >> 2, qy = (m >> 1) & 1, qx = m & 1;
            int ky = pr - qy, kx = pc - qx;
            if ((unsigned)ky < 5u && (unsigned)kx < 5u)
                v = w2[(oc * 4 + ic) * 25 + ky * 5 + kx];
        }
        w2F[i] = (_Float16)v;
    }
    for (int i = t; i < 10 * 512; i += stride) {      // wxF
        int j = i & 7, l = (i >> 3) & 63, q = i >> 9;
        int g = l >> 5, m = l & 31;
        int k = q * 16 + g * 8 + j;
        int pr = k >> 5, pc = (k >> 2) & 7, ic = k & 3;
        int og = (m & 3) * 8 + (m >> 2);
        float v = (pr < 5 && pc < 5) ? wx[(og * 4 + ic) * 25 + pr * 5 + pc] : 0.f;
        wxF[i] = (_Float16)v;
    }
    for (int i = t; i < 14 * 512; i += stride) {      // whF (j = ch' order)
        int j = i & 7, l = (i >> 3) & 63, q = i >> 9;
        int g = l >> 5, m = l & 31;
        int og = (m & 3) * 8 + (m >> 2);
        int tap = 2 * q + g;
        int icj = 2 * (j & 3) + (j >> 2);
        float v = (tap < 25) ? wh[(og * 8 + icj) * 25 + tap] : 0.f;
        whF[i] = (_Float16)v;
    }
    if (t < 32) {
        int og = (t & 3) * 8 + (t >> 2);
        btot[t] = bx[og] + bh[og];
    }
    float4 z4 = make_float4(0.f, 0.f, 0.f, 0.f);
    for (int i = t; i < 262144; i += stride) ((float4*)cfr)[i] = z4;  // 4MB
    for (int i = t; i < 131072; i += stride) ((float4*)hA)[i]  = z4;  // 2MB
}

// ---------------------------------------------------------------------------
// k1: conv 1->4 + relu + maxpool2 as MFMA (pool-in-M). r8 verified verbatim.
// ---------------------------------------------------------------------------
__global__ __launch_bounds__(256, 4) void k1_mfma(
    const float* __restrict__ obs, const _Float16* __restrict__ wk1F,
    const float* __restrict__ b1, _Float16* __restrict__ s1cl)
{
    __shared__ _Float16 lds[36 * 264];
    u32* ldsu = (u32*)lds;
    int tid = threadIdx.x;
    int lane = tid & 63, w = tid >> 6, g = lane >> 5;
    int yt = blockIdx.x & 7;
    int tb = blockIdx.x >> 3;
    const float* in = obs + ((size_t)tb << 16);

    f16x8 wk1[3];
    #pragma unroll
    for (int q = 0; q < 3; ++q)
        wk1[q] = *(const f16x8*)(wk1F + ((size_t)q * 64 + lane) * 8);
    float bA = b1[g], bB = b1[g + 2];

    for (int i = tid; i < 36 * 132; i += 256) ldsu[i] = 0;
    __syncthreads();
    for (int i = tid; i < 36 * 64; i += 256) {
        int r = i >> 6, c4 = i & 63;
        int gy = (yt << 5) - 2 + r;
        if ((unsigned)gy < 256u) {
            float4 v = *(const float4*)(in + (gy << 8) + (c4 << 2));
            union { _Float16 h[2]; u32 u; } p0, p1;
            p0.h[0] = (_Float16)v.x; p0.h[1] = (_Float16)v.y;
            p1.h[0] = (_Float16)v.z; p1.h[1] = (_Float16)v.w;
            int ui = r * 132 + 1 + 2 * c4;
            ldsu[ui]     = p0.u;
            ldsu[ui + 1] = p1.u;
        }
    }
    __syncthreads();

    int y0 = yt << 4;
    #pragma unroll
    for (int i = 0; i < 16; ++i) {
        int py_loc = (w << 2) + (i >> 2);
        int px0 = (i & 3) << 5;
        int n = px0 + (lane & 31);
        const u32* lp = ldsu + (2 * py_loc + g) * 132 + n;

        f32x16 acc;
        #pragma unroll
        for (int r = 0; r < 16; ++r) acc[r] = 0.f;

        #pragma unroll
        for (int q = 0; q < 3; ++q) {
            union { f16x8 v; u32 u[4]; } bb;
            const u32* p = lp + (2 * q) * 132;
            bb.u[0] = p[0]; bb.u[1] = p[1]; bb.u[2] = p[2]; bb.u[3] = p[3];
            acc = __builtin_amdgcn_mfma_f32_32x32x16_f16(wk1[q], bb.v, acc, 0, 0, 0);
        }

        float mA = fmaxf(fmaxf(fmaxf(acc[0], acc[1]), fmaxf(acc[2], acc[3])) + bA, 0.f);
        float mB = fmaxf(fmaxf(fmaxf(acc[4], acc[5]), fmaxf(acc[6], acc[7])) + bB, 0.f);

        int pix = ((y0 + py_loc) << 7) + n;
        _Float16* dst = s1cl + (((size_t)tb << 14) + pix) * 4;
        dst[g]     = (_Float16)mA;
        dst[g + 2] = (_Float16)mB;
    }
}

// ---------------------------------------------------------------------------
// k2: conv 4->4 + relu + maxpool2 as MFMA (pool-in-M). r8 verified verbatim.
// ---------------------------------------------------------------------------
__global__ __launch_bounds__(256) void k2_mfma(
    const _Float16* __restrict__ s1cl, const _Float16* __restrict__ w2F,
    const float* __restrict__ b2, _Float16* __restrict__ s2cl)
{
    __shared__ _Float16 lds[20 * 136 * 4];
    int tid = threadIdx.x;
    int lane = tid & 63, w = tid >> 6, g = lane >> 5;
    int f  = blockIdx.x >> 3;
    int yt = blockIdx.x & 7;
    int y0 = yt << 3;

    f16x8 wf[12];
    #pragma unroll
    for (int q = 0; q < 12; ++q)
        wf[q] = *(const f16x8*)(w2F + ((size_t)q * 64 + lane) * 8);

    float bA = b2[g], bB = b2[g + 2];

    for (int i = tid; i < 20 * 68; i += 256) {
        int r = i / 68, u = i % 68;
        int gy = (yt << 4) - 2 + r;
        int gx = 2 * u - 2;
        f16x8 v = f16x8_zero();
        if ((unsigned)gy < 128u && (unsigned)gx < 127u)
            v = *(const f16x8*)(s1cl + ((((size_t)f << 14) + (gy << 7) + gx) << 2));
        *(f16x8*)&lds[(r * 136 + 2 * u) * 4] = v;
    }
    __syncthreads();

    #pragma unroll
    for (int i = 0; i < 4; ++i) {
        int ct = w * 4 + i;
        int ly = ct >> 1, hx = ct & 1;
        int px = hx * 32 + (lane & 31);
        int base = (2 * ly) * 1088 + (2 * px) * 8 + g * 16;

        f32x16 acc;
        #pragma unroll
        for (int r = 0; r < 16; ++r) acc[r] = 0.f;

        #pragma unroll
        for (int q = 0; q < 12; ++q) {
            f16x8 bv = *(const f16x8*)((const char*)lds + base +
                                       ((q >> 1) * 1088 + (q & 1) * 32));
            acc = __builtin_amdgcn_mfma_f32_32x32x16_f16(wf[q], bv, acc, 0, 0, 0);
        }

        float mA = fmaxf(fmaxf(fmaxf(acc[0], acc[1]), fmaxf(acc[2], acc[3])) + bA, 0.f);
        float mB = fmaxf(fmaxf(fmaxf(acc[4], acc[5]), fmaxf(acc[6], acc[7])) + bB, 0.f);

        int pix = ((y0 + ly) << 6) + px;
        _Float16* dst = s2cl + ((((size_t)f << 12) + pix) << 2);
        dst[g]     = (_Float16)mA;
        dst[g + 2] = (_Float16)mB;
    }
}

// ---------------------------------------------------------------------------
// k4x: one ConvLSTM step with k3 FUSED (wx-conv computed on the fly from s2).
//   Per tile: acc = btot; 10 wx-MFMA chunks (B from 6x72x4 s2 LDS tile,
//   byte-identical gather to verified k3); 14 wh-MFMA chunks (B from 6x68x8
//   h LDS tile, as verified k4v2); then the in-lane LSTM epilogue.
//   c in cfr f32 fragment layout (in-place); h ping-pong f16 [pix][ch'].
//   whF loads placed AFTER the wx loop so wxF regs (40) die before whF (56).
// ---------------------------------------------------------------------------
__global__ __launch_bounds__(256, 4) void k4x(
    const _Float16* __restrict__ s2t, const _Float16* __restrict__ hprev,
    const _Float16* __restrict__ wxF, const _Float16* __restrict__ whF,
    const float* __restrict__ btot, float* __restrict__ cfr,
    const float* __restrict__ wci, const float* __restrict__ wcf,
    const float* __restrict__ wco, _Float16* __restrict__ hnext,
    float* __restrict__ out_hc, int last)
{
    __shared__ _Float16 sH[6 * 68 * 8];      // 6528 B, pitch 1088
    __shared__ _Float16 sS[6 * 72 * 4];      // 3456 B, pitch 576
    int tid = threadIdx.x;
    int lane = tid & 63, w = tid >> 6, g = lane >> 5;
    int b  = blockIdx.x >> 5;
    int y0 = (blockIdx.x & 31) << 1;

    int ly = w >> 1, hx = w & 1;
    int px = hx * 32 + (lane & 31);
    int pix = ((y0 + ly) << 6) + px;
    size_t tl = (size_t)b * 128 + (y0 + ly) * 2 + hx;

    // early independent loads
    float4 cv = *(const float4*)(cfr + tl * 256 + lane * 4);
    float pci[4], pcf[4], pco[4];
    #pragma unroll
    for (int cc = 0; cc < 4; ++cc) {
        int ppix = ((2 * cc + g) << 12) + pix;
        pci[cc] = wci[ppix];
        pcf[cc] = wcf[ppix];
        pco[cc] = wco[ppix];
    }

    // stage h tile (rows y0-2..y0+3, cols -2..65)
    for (int i = tid; i < 6 * 68; i += 256) {
        int r = i / 68, u = i % 68;
        int gy = y0 - 2 + r;
        int gx = u - 2;
        f16x8 v = f16x8_zero();
        if ((unsigned)gy < 64u && (unsigned)gx < 64u)
            v = *(const f16x8*)(hprev + ((((size_t)b << 12) + (gy << 6) + gx) << 3));
        *(f16x8*)&sH[(r * 68 + u) * 8] = v;
    }
    // stage s2 tile (rows y0-2..y0+3, cols -2..69; k3-style pair staging)
    for (int i = tid; i < 6 * 36; i += 256) {
        int r = i / 36, u = i % 36;
        int gy = y0 - 2 + r;
        int gx = 2 * u - 2;
        f16x8 v = f16x8_zero();
        if ((unsigned)gy < 64u && (unsigned)gx < 63u)
            v = *(const f16x8*)(s2t + ((((size_t)b << 12) + (gy << 6) + gx) << 2));
        *(f16x8*)&sS[(r * 72 + 2 * u) * 4] = v;
    }
    __syncthreads();

    // acc init = folded biases (bx+bh), fragment rows
    f32x16 acc;
    #pragma unroll
    for (int r = 0; r < 16; ++r) {
        int row0 = (r & 3) + 8 * (r >> 2);
        acc[r] = g ? btot[row0 + 4] : btot[row0];
    }

    // wx conv (k3's gather, 6-row tile): base = ly*576 + px*8 + g*16
    {
        int baseS = ly * 576 + px * 8 + g * 16;
        #pragma unroll
        for (int q = 0; q < 10; ++q) {
            f16x8 wv = *(const f16x8*)(wxF + ((size_t)q * 64 + lane) * 8);
            f16x8 bv = *(const f16x8*)((const char*)sS + baseS +
                                       ((q >> 1) * 576 + (q & 1) * 32));
            acc = __builtin_amdgcn_mfma_f32_32x32x16_f16(wv, bv, acc, 0, 0, 0);
        }
    }

    // wh conv (k4v2's gather): base = ly*1088 + px*16
    {
        int baseH = ly * 1088 + px * 16;
        #pragma unroll
        for (int q = 0; q < 14; ++q) {
            int t0 = 2 * q, t1 = 2 * q + 1;
            int o0 = TKY(t0) * 1088 + TKX(t0) * 16;
            int o1 = TKY(t1) * 1088 + TKX(t1) * 16;
            int toff = g ? o1 : o0;
            f16x8 wv = *(const f16x8*)(whF + ((size_t)q * 64 + lane) * 8);
            f16x8 bv = *(const f16x8*)((const char*)sH + baseH + toff);
            acc = __builtin_amdgcn_mfma_f32_32x32x16_f16(wv, bv, acc, 0, 0, 0);
        }
    }

    // LSTM epilogue (r8 k4v2 verbatim)
    float cvv[4] = {cv.x, cv.y, cv.z, cv.w};
    float cn4[4];
    f16x4 hv;
    #pragma unroll
    for (int cc = 0; cc < 4; ++cc) {
        float c_old = cvv[cc];
        float i_ = fast_sigmoid(acc[4 * cc + 0] + c_old * pci[cc]);
        float f_ = fast_sigmoid(acc[4 * cc + 1] + c_old * pcf[cc]);
        float cn = f_ * c_old + i_ * fast_tanh(acc[4 * cc + 2]);
        float o_ = fast_sigmoid(acc[4 * cc + 3] + cn * pco[cc]);
        float hn = o_ * fast_tanh(cn);
        cn4[cc] = cn;
        hv[cc] = (_Float16)hn;
        if (last) {
            int ch = 2 * cc + g;
            size_t sidx = (((size_t)b * 8 + ch) << 12) + pix;
            out_hc[sidx] = hn;
            out_hc[sidx + 1048576] = cn;
        }
    }
    if (!last) {
        *(float4*)(cfr + tl * 256 + lane * 4) =
            make_float4(cn4[0], cn4[1], cn4[2], cn4[3]);
        *(f16x4*)(hnext + ((((size_t)b << 12) + pix) << 3) + 4 * g) = hv;
    }
}

// ---------------------------------------------------------------------------
extern "C" void kernel_launch(void* const* d_in, const int* in_sizes, int n_in,
                              void* d_out, int out_size, void* d_ws, size_t ws_size,
                              hipStream_t stream)
{
    const float* obs = (const float*)d_in[0];
    const float* w1  = (const float*)d_in[1];
    const float* b1  = (const float*)d_in[2];
    const float* w2  = (const float*)d_in[3];
    const float* b2  = (const float*)d_in[4];
    const float* wx  = (const float*)d_in[5];
    const float* bx  = (const float*)d_in[6];
    const float* wh  = (const float*)d_in[7];
    const float* bh  = (const float*)d_in[8];
    const float* wci = (const float*)d_in[9];
    const float* wcf = (const float*)d_in[10];
    const float* wco = (const float*)d_in[11];

    char* wsb = (char*)d_ws;
    // byte layout (xg eliminated — k3 fused into k4x):
    //   [0, 33,554,432)             s1cl f16 [256][16384][4]
    //   [33,554,432, 41,943,040)    s2cl f16 [256][4096][4]
    //   [41,943,040, 44,040,192)    hA f16
    //   [44,040,192, 46,137,344)    hB f16
    //   [46,137,344, 50,331,648)    cfr f32 [4096 tl][64][4]
    //   [50,331,648, ...)           w2F, wxF, whF, wk1F, btot
    _Float16* s1cl = (_Float16*)wsb;
    _Float16* s2cl = (_Float16*)(wsb + 33554432);
    _Float16* hA   = (_Float16*)(wsb + 41943040);
    _Float16* hB   = (_Float16*)(wsb + 44040192);
    float*    cfr  = (float*)(wsb + 46137344);
    _Float16* w2F  = (_Float16*)(wsb + 50331648);
    _Float16* wxF  = (_Float16*)(wsb + 50343936);
    _Float16* whF  = (_Float16*)(wsb + 50354176);
    _Float16* wk1F = (_Float16*)(wsb + 50368512);
    float*    btot = (float*)(wsb + 50371584);

    kT_prep<<<64, 256, 0, stream>>>(w1, w2, wx, wh, bx, bh,
                                    wk1F, w2F, wxF, whF, btot, cfr, hA);

    k1_mfma<<<2048, 256, 0, stream>>>(obs, wk1F, b1, s1cl);
    k2_mfma<<<2048, 256, 0, stream>>>(s1cl, w2F, b2, s2cl);

    float* outp = (float*)d_out;
    for (int t = 0; t < 8; ++t) {
        const _Float16* hp = (t & 1) ? hB : hA;
        _Float16*       hn = (t & 1) ? hA : hB;
        k4x<<<1024, 256, 0, stream>>>(
            s2cl + (size_t)t * 524288, hp, wxF, whF, btot, cfr,
            wci, wcf, wco, hn, outp, t == 7);
    }
}